// Round 13
// baseline (124.129 us; speedup 1.0000x reference)
//
#include <hip/hip_runtime.h>

// ---- problem constants ----
#define CIN   16
#define COUTC 8
#define HIN   8
#define WINW  8
#define SST   2
#define PPD   1
#define HOUTC 16
#define WOUTC 16
#define IN_F  2304   // CIN*3*3*4*4
#define OUT_F 4608   // COUT*3*3*8*8
#define BATCH 64

// ---- gemm decomposition ----
// Block = 6 waves x 16 disjoint o-rows = 96 rows  (acts amortized 2x vs R9).
// Grid = (OUT_F/96) * OS = 48*16 = 768 = EXACTLY 3 blocks/CU (18 waves/CU).
// os%8 == XCD -> act chunks (144KB x2) stay L2-pinned per XCD.
#define OS    16            // K-splits
#define FC    (IN_F / OS)   // 144 f per block
#define SF    16            // f's per LDS subtile
#define NSUB  (FC / SF)     // 9 subtiles
#define NWAVE 6             // waves per block
#define ROWS  96            // o-rows per block

typedef __bf16 bf16x8 __attribute__((ext_vector_type(8)));
typedef float  f32x4  __attribute__((ext_vector_type(4)));

// uniform knot grid: g[t] = (t-3)*0.4 - 1
__device__ __forceinline__ float gridv(int t) {
    return (float)(t - 3) * 0.4f - 1.0f;
}

// async global->LDS: per-lane global src, wave-uniform LDS base (+lane*16 by HW)
__device__ __forceinline__ void gload_lds16(const float* g, float* l) {
    __builtin_amdgcn_global_load_lds(
        (const __attribute__((address_space(1))) unsigned int*)g,
        (__attribute__((address_space(3))) unsigned int*)l, 16, 0, 0);
}

// ---------------------------------------------------------------
// prep: u = unfold(x); activations bf16 packed in lane-linear
// MFMA B-fragment chunks (1KB per (f-group, b-group) chunk).
//   spline: chunk C = (f>>2)*4 + (b>>4); slot = (f&3)*16 + (b&15)
//   base:   chunk C = (f>>5)*4 + (b>>4); slot = ((f>>3)&3)*16 + (b&15), elem f&7
// ---------------------------------------------------------------
__global__ __launch_bounds__(256) void prep_kernel(const float* __restrict__ x,
                                                   __bf16* __restrict__ Abb,
                                                   __bf16* __restrict__ Bsb) {
    int tid = blockIdx.x * 256 + threadIdx.x;   // tid = f*64 + b
    if (tid >= IN_F * BATCH) return;
    int f = tid >> 6, b = tid & 63;
    int ckk = f >> 4, s = f & 15;
    int c = ckk / 9, r = ckk % 9;
    int ki = r / 3, kj = r % 3;
    int oh = s >> 2, ow = s & 3;
    int h = ki + oh * SST - PPD;
    int w = kj + ow * SST - PPD;
    float u = 0.0f;
    if (h >= 0 && h < HIN && w >= 0 && w < WINW)
        u = x[((b * CIN + c) * HIN + h) * WINW + w];

    // base activation (silu)
    {
        size_t idx = ((size_t)((f >> 5) * 4 + (b >> 4))) * 512
                   + (((f >> 3) & 3) * 16 + (b & 15)) * 8 + (f & 7);
        Abb[idx] = (__bf16)(u / (1.0f + __expf(-u)));
    }

    // degree-3 B-spline bases (Cox-de Boor, matches reference)
    float bs[11];
#pragma unroll
    for (int t = 0; t < 11; ++t)
        bs[t] = (u >= gridv(t) && u < gridv(t + 1)) ? 1.0f : 0.0f;
#pragma unroll
    for (int k = 1; k <= 3; ++k) {
#pragma unroll
        for (int i = 0; i < 11; ++i) {
            if (i < 11 - k) {
                float g_i  = gridv(i);
                float g_ik = gridv(i + k);
                float g_i1 = gridv(i + 1);
                float g_k1 = gridv(i + k + 1);
                bs[i] = (u - g_i) / (g_ik - g_i) * bs[i]
                      + (g_k1 - u) / (g_k1 - g_i1) * bs[i + 1];
            }
        }
    }
    bf16x8 v;
#pragma unroll
    for (int t = 0; t < 8; ++t) v[t] = (__bf16)bs[t];
    size_t frag = ((size_t)((f >> 2) * 4 + (b >> 4))) * 64
                + (f & 3) * 16 + (b & 15);
    ((bf16x8*)Bsb)[frag] = v;
}

// ---------------------------------------------------------------
// MFMA GEMM. Weights fp32 streamed direct to registers (cvt bf16);
// activations + spline_scaler staged to LDS (acts amortized over 96 rows).
// Block: 6 waves x 16 DISJOINT o-rows; wave: 16 o x 64 b; no cross-wave
// reduce. Grid 768 = 3 blocks/CU exactly; os%8 == XCD.
// ---------------------------------------------------------------
__global__ __launch_bounds__(384) void gemm_kernel(
    const float* __restrict__ Wb,    // (OUT_F, IN_F)
    const float* __restrict__ Ws,    // (OUT_F, IN_F, 8)
    const float* __restrict__ Sc,    // (OUT_F, IN_F)
    const __bf16* __restrict__ Abb,  // base B-frags (packed chunks)
    const __bf16* __restrict__ Bsb,  // spline B-frags (packed chunks)
    float* __restrict__ partial)     // (OS, OUT_F, 64)
{
    // LDS: acts [2][16KB] + sc [2][6KB] = 44 KB -> 3 blocks/CU
    __shared__ __align__(16) char smem[2 * 16384 + 2 * 6144];
    char*  alds = smem;                        // [2][16 KB] act subtile
    float* scb  = (float*)(smem + 32768);      // [2][1536 f32] sc [96 o][16 f]

    const int tid  = threadIdx.x;
    const int lane = tid & 63;
    const int wv   = tid >> 6;       // 0..5
    const int lr   = lane & 15;      // o-in-wave-tile / b-in-frag
    const int lg   = lane >> 4;      // k-group
    const int ot = blockIdx.x / OS;  // 0..47
    const int os = blockIdx.x % OS;  // os%8 == XCD under round-robin dispatch
    const int o0 = ot * ROWS;
    const int f0 = os * FC;
    const int R  = wv * 16 + lr;     // row within block tile (0..95)
    const int o  = o0 + R;           // this lane's weight row

    f32x4 acc0 = {0.f,0.f,0.f,0.f}, acc1 = {0.f,0.f,0.f,0.f};
    f32x4 acc2 = {0.f,0.f,0.f,0.f}, acc3 = {0.f,0.f,0.f,0.f};

    // ---- stage act subtile t (16 KB): 16 x 1KB instrs over 6 waves ----
    auto stage_act = [&](int t, int pb) {
        const char* src = (const char*)Bsb + (size_t)(f0 + t * SF) * 1024;
        char* dst = alds + pb * 16384;
        for (int i = wv; i < 16; i += NWAVE)
            gload_lds16((const float*)(src + i * 1024) + lane * 4,
                        (float*)(dst + i * 1024));
    };
    // ---- stage sc subtile t (96 o x 16 f = 6 KB): exactly 1 instr/wave ----
    // wave wv covers rows [wv*16, wv*16+16); lane covers row wv*16+(lane>>2),
    // f-quad (lane&3)*4. LDS float idx = wv*256 + lane*4 (+elem) ->
    // scl[R*16 + j] with j = f-within-subtile. No OOB, no cross-buffer.
    auto stage_sc = [&](int t, int pb) {
        const int r  = wv * 16 + (lane >> 2);
        const int fq = (lane & 3) * 4;
        gload_lds16(Sc + (size_t)(o0 + r) * IN_F + f0 + t * SF + fq,
                    scb + pb * 1536 + wv * 256);
    };

    const float* wp = Ws + ((size_t)o * IN_F + f0 + lg) * 8;

    stage_act(0, 0);
    stage_sc(0, 0);
    __syncthreads();

    for (int t = 0; t < NSUB; ++t) {
        const int pb = t & 1;
        if (t + 1 < NSUB) {
            stage_act(t + 1, pb ^ 1);
            stage_sc(t + 1, pb ^ 1);
        }

        const char*  ab  = alds + pb * 16384;
        const float* scl = scb + pb * 1536;
#pragma unroll
        for (int s = 0; s < SF / 4; ++s) {          // 4 K-steps
            float4 w0 = *(const float4*)(wp + (size_t)(t * SF + s * 4) * 8);
            float4 w1 = *(const float4*)(wp + (size_t)(t * SF + s * 4) * 8 + 4);
            float  sc = scl[R * 16 + s * 4 + lg];
            bf16x8 b0 = *(const bf16x8*)(ab + s * 4096 +    0 + lane * 16);
            bf16x8 b1 = *(const bf16x8*)(ab + s * 4096 + 1024 + lane * 16);
            bf16x8 b2 = *(const bf16x8*)(ab + s * 4096 + 2048 + lane * 16);
            bf16x8 b3 = *(const bf16x8*)(ab + s * 4096 + 3072 + lane * 16);
            bf16x8 af;
            af[0] = (__bf16)(w0.x * sc); af[1] = (__bf16)(w0.y * sc);
            af[2] = (__bf16)(w0.z * sc); af[3] = (__bf16)(w0.w * sc);
            af[4] = (__bf16)(w1.x * sc); af[5] = (__bf16)(w1.y * sc);
            af[6] = (__bf16)(w1.z * sc); af[7] = (__bf16)(w1.w * sc);
            acc0 = __builtin_amdgcn_mfma_f32_16x16x32_bf16(af, b0, acc0, 0, 0, 0);
            acc1 = __builtin_amdgcn_mfma_f32_16x16x32_bf16(af, b1, acc1, 0, 0, 0);
            acc2 = __builtin_amdgcn_mfma_f32_16x16x32_bf16(af, b2, acc2, 0, 0, 0);
            acc3 = __builtin_amdgcn_mfma_f32_16x16x32_bf16(af, b3, acc3, 0, 0, 0);
        }
        __syncthreads();   // drains stage(t+1), guards buffer reuse
    }

    // ---- base GEMM: 72 global K-steps of 32 f, split 5/4 over 16 os ----
    const int nbs = (os < 8) ? 5 : 4;
    const int sb0 = (os < 8) ? os * 5 : 40 + (os - 8) * 4;
    for (int s = 0; s < nbs; ++s) {
        const int fb = (sb0 + s) * 32;
        const float* wbp = Wb + (size_t)o * IN_F + fb + lg * 8;
        const bf16x8* ap = (const bf16x8*)Abb + ((size_t)fb >> 5) * 256 + lane;
        float4 w0 = *(const float4*)wbp;
        float4 w1 = *(const float4*)(wbp + 4);
        bf16x8 b0 = ap[0];
        bf16x8 b1 = ap[64];
        bf16x8 b2 = ap[128];
        bf16x8 b3 = ap[192];
        bf16x8 af;
        af[0] = (__bf16)w0.x; af[1] = (__bf16)w0.y;
        af[2] = (__bf16)w0.z; af[3] = (__bf16)w0.w;
        af[4] = (__bf16)w1.x; af[5] = (__bf16)w1.y;
        af[6] = (__bf16)w1.z; af[7] = (__bf16)w1.w;
        acc0 = __builtin_amdgcn_mfma_f32_16x16x32_bf16(af, b0, acc0, 0, 0, 0);
        acc1 = __builtin_amdgcn_mfma_f32_16x16x32_bf16(af, b1, acc1, 0, 0, 0);
        acc2 = __builtin_amdgcn_mfma_f32_16x16x32_bf16(af, b2, acc2, 0, 0, 0);
        acc3 = __builtin_amdgcn_mfma_f32_16x16x32_bf16(af, b3, acc3, 0, 0, 0);
    }

    // ---- epilogue: waves own disjoint o's -> direct coalesced store ----
    // D layout: lane holds D[lg*4 + r][lr]; b = j*16 + lr
#pragma unroll
    for (int r = 0; r < 4; ++r) {
        const size_t row = (size_t)os * OUT_F + o0 + wv * 16 + lg * 4 + r;
        partial[row * 64 +  0 + lr] = acc0[r];
        partial[row * 64 + 16 + lr] = acc1[r];
        partial[row * 64 + 32 + lr] = acc2[r];
        partial[row * 64 + 48 + lr] = acc3[r];
    }
}

// ---------------------------------------------------------------
// fold + OS-reduce, inverted mapping: one thread per OUTPUT element.
// No atomics, no memset.
// ---------------------------------------------------------------
__global__ __launch_bounds__(256) void fold_kernel(const float* __restrict__ partial,
                                                   float* __restrict__ out) {
    int gid = blockIdx.x * 256 + threadIdx.x;     // 131072 = 64*8*16*16
    int b = gid & 63, p = gid >> 6;
    int w = p & 15, h = (p >> 4) & 15, c = p >> 8;
    float sum = 0.0f;
#pragma unroll
    for (int ki = 0; ki < 3; ++ki) {
        int th = h + 1 - ki;
        if (th < 0 || (th & 1) || (th >> 1) >= 8) continue;
        int oh = th >> 1;
#pragma unroll
        for (int kj = 0; kj < 3; ++kj) {
            int tw = w + 1 - kj;
            if (tw < 0 || (tw & 1) || (tw >> 1) >= 8) continue;
            int ow = tw >> 1;
            int o = ((c * 3 + ki) * 3 + kj) * 64 + oh * 8 + ow;
            const float* pp = partial + (size_t)o * 64 + b;
#pragma unroll
            for (int osl = 0; osl < OS; ++osl)
                sum += pp[(size_t)osl * (OUT_F * 64)];
        }
    }
    out[((b * COUTC + c) * HOUTC + h) * WOUTC + w] = sum;
}

extern "C" void kernel_launch(void* const* d_in, const int* in_sizes, int n_in,
                              void* d_out, int out_size, void* d_ws, size_t ws_size,
                              hipStream_t stream) {
    const float* x  = (const float*)d_in[0];
    const float* Wb = (const float*)d_in[1];
    const float* Ws = (const float*)d_in[2];
    const float* Sc = (const float*)d_in[3];
    // d_in[4] = grid, recomputed analytically (uniform knots)

    float* out = (float*)d_out;

    __bf16* Abb     = (__bf16*)d_ws;                              // IN_F*64 bf16 (288 KB)
    __bf16* Bsb     = Abb + (size_t)IN_F * BATCH;                 // IN_F*64*8 bf16 (2.25 MB)
    float*  partial = (float*)(Bsb + (size_t)IN_F * BATCH * 8);   // OS*OUT_F*64 f32 (18.9 MB)

    prep_kernel<<<(IN_F * BATCH + 255) / 256, 256, 0, stream>>>(x, Abb, Bsb);

    gemm_kernel<<<(OUT_F / ROWS) * OS, 384, 0, stream>>>(Wb, Ws, Sc, Abb, Bsb, partial);

    fold_kernel<<<(BATCH * COUTC * HOUTC * WOUTC) / 256, 256, 0, stream>>>(partial, out);
}